// Round 1
// baseline (193.122 us; speedup 1.0000x reference)
//
#include <hip/hip_runtime.h>
#include <cstdint>
#include <cstddef>

using f16   = _Float16;
using f16x4 = __attribute__((ext_vector_type(4))) _Float16;
using f16x8 = __attribute__((ext_vector_type(8))) _Float16;
using f32x4 = __attribute__((ext_vector_type(4))) float;

__device__ __forceinline__ f32x4 mfma16(f16x8 a, f16x8 b, f32x4 c) {
  return __builtin_amdgcn_mfma_f32_16x16x32_f16(a, b, c, 0, 0, 0);
}

__device__ __forceinline__ void gld16(const f16* g, f16* l) {
  __builtin_amdgcn_global_load_lds(
      (__attribute__((address_space(1))) void*)g,
      (__attribute__((address_space(3))) void*)l, 16, 0, 0);
}

constexpr int BATCH = 2, SEQL = 2048, HID = 1024, NH = 16, DH = 64;
constexpr int TOK = BATCH * SEQL;   // 4096
constexpr int NQKV = 3 * HID;       // 3072

// ---------------------------------------------------------------- prep
__global__ __launch_bounds__(256) void k_convert_x(const float* __restrict__ x,
                                                   f16* __restrict__ xh) {
  int i = (blockIdx.x * 256 + threadIdx.x) * 4;
  float4 v = *(const float4*)(x + i);
  f16x4 o = { (f16)v.x, (f16)v.y, (f16)v.z, (f16)v.w };
  *(f16x4*)(xh + i) = o;
}

__global__ __launch_bounds__(256) void k_transpose(const float* __restrict__ Wq,
                                                   const float* __restrict__ Wk,
                                                   const float* __restrict__ Wv,
                                                   const float* __restrict__ Wo,
                                                   f16* __restrict__ WT,
                                                   f16* __restrict__ WoT) {
  __shared__ float tile[32][33];
  int mat = blockIdx.z;
  const float* W = (mat == 0) ? Wq : (mat == 1) ? Wk : (mat == 2) ? Wv : Wo;
  int in0 = blockIdx.x * 32, out0 = blockIdx.y * 32;
  int c = threadIdx.x & 31, r8 = threadIdx.x >> 5;
#pragma unroll
  for (int i = 0; i < 4; i++) {
    int r = r8 + i * 8;
    tile[r][c] = W[(size_t)(in0 + r) * HID + out0 + c];
  }
  __syncthreads();
#pragma unroll
  for (int i = 0; i < 4; i++) {
    int r = r8 + i * 8;
    f16 v = (f16)tile[c][r];
    if (mat == 3) WoT[(size_t)(out0 + r) * HID + in0 + c] = v;
    else          WT[(size_t)(mat * HID + out0 + r) * HID + in0 + c] = v;
  }
}

// ---------------------------------------------------------------- QKV GEMM
// 128x128 block tile, BK=32, async staging. V is stored TRANSPOSED [d][key']
// with keys pre-permuted (key'=(k&~31)|((k&12)<<1)|((k>>2)&4)|(k&3)) so the
// attention kernel's V A-fragments are contiguous 16B LDS reads.
__global__ __launch_bounds__(256, 2) void k_gemm_qkv(
    const f16* __restrict__ xh, const f16* __restrict__ WT,
    const float* __restrict__ bq, const float* __restrict__ bk,
    const float* __restrict__ bv,
    f16* __restrict__ Qh, f16* __restrict__ Kh, f16* __restrict__ Vp) {
  constexpr int K = HID;
  int m0 = blockIdx.x * 128, n0 = blockIdx.y * 128;
  int tid = threadIdx.x;
  int w = tid >> 6, lane = tid & 63, lr = lane & 15, lq = lane >> 4;
  int wm = w >> 1, wn = w & 1;
  __shared__ f16 Ash[128 * 32];
  __shared__ f16 Bsh[128 * 32];
  f32x4 acc[4][4];
#pragma unroll
  for (int i = 0; i < 4; i++)
#pragma unroll
    for (int j = 0; j < 4; j++) acc[i][j] = (f32x4){0.f, 0.f, 0.f, 0.f};

  int row0 = tid >> 2, seg0 = tid & 3;
  int row1 = (256 + tid) >> 2;
  const f16* Ag0 = xh + (size_t)(m0 + row0) * K + seg0 * 8;
  const f16* Ag1 = xh + (size_t)(m0 + row1) * K + seg0 * 8;
  const f16* Bg0 = WT + (size_t)(n0 + row0) * K + seg0 * 8;
  const f16* Bg1 = WT + (size_t)(n0 + row1) * K + seg0 * 8;

  for (int k0 = 0; k0 < K; k0 += 32) {
    __syncthreads();
    gld16(Ag0 + k0, Ash + tid * 8);
    gld16(Ag1 + k0, Ash + (256 + tid) * 8);
    gld16(Bg0 + k0, Bsh + tid * 8);
    gld16(Bg1 + k0, Bsh + (256 + tid) * 8);
    __syncthreads();
    f16x8 af[4], bfr[4];
#pragma unroll
    for (int mt = 0; mt < 4; mt++)
      af[mt] = *(const f16x8*)(Ash + (wm * 64 + mt * 16 + lr) * 32 + lq * 8);
#pragma unroll
    for (int nt = 0; nt < 4; nt++)
      bfr[nt] = *(const f16x8*)(Bsh + (wn * 64 + nt * 16 + lr) * 32 + lq * 8);
#pragma unroll
    for (int mt = 0; mt < 4; mt++)
#pragma unroll
      for (int nt = 0; nt < 4; nt++)
        acc[mt][nt] = mfma16(af[mt], bfr[nt], acc[mt][nt]);
  }

#pragma unroll
  for (int nt = 0; nt < 4; nt++) {
    int o = n0 + wn * 64 + nt * 16 + lr;
    int sec = o >> 10, o1 = o & 1023, hh = o1 >> 6, dd = o1 & 63;
    float bias = (sec == 0) ? bq[o1] : (sec == 1) ? bk[o1] : bv[o1];
#pragma unroll
    for (int mt = 0; mt < 4; mt++) {
      int t0 = m0 + wm * 64 + mt * 16 + lq * 4;
      int b = t0 >> 11, s0 = t0 & (SEQL - 1);
      size_t bh = (size_t)(b * NH + hh);
      if (sec == 2) {
        f16x4 pv = { (f16)(acc[mt][nt][0] + bias), (f16)(acc[mt][nt][1] + bias),
                     (f16)(acc[mt][nt][2] + bias), (f16)(acc[mt][nt][3] + bias) };
        int pb = (s0 & ~31) | ((s0 & 12) << 1) | ((s0 >> 2) & 4);
        *(f16x4*)(Vp + (bh * DH + dd) * SEQL + pb) = pv;   // V^T, permuted keys
      } else {
        f16* dst = (sec == 0) ? Qh : Kh;
#pragma unroll
        for (int r = 0; r < 4; r++)
          dst[(bh * SEQL + s0 + r) * DH + dd] = (f16)(acc[mt][nt][r] + bias);
      }
    }
  }
}

// ---------------------------------------------------------------- attention
// grid (x=bh 32, y=qblk 8): bh fastest => all blocks of one bh land on the
// same XCD (id%8 = bh%8) -> K/V stay L2-resident (4 bh x 512KB = 2MB/XCD).
// 256 q/block, 4 waves x 64 q (4 q-tiles of 16). Each K/V fragment read from
// LDS now feeds 4 MFMAs (was 2) -> LDS-pipe demand halves; kernel flips from
// LDS-bound to MFMA-bound. 1 block/CU, so high VGPR use is free.
// S computed transposed (A=K, B=Q); softmax over keys is in-lane, P's
// B-fragment is the packed exp results (no LDS trip).
// Double-buffered LDS + register prefetch: ONE barrier per key tile.
__global__ __launch_bounds__(256, 1) void k_attn(const f16* __restrict__ Qh,
                                                 const f16* __restrict__ Kh,
                                                 const f16* __restrict__ Vp,
                                                 f16* __restrict__ Ao) {
  int bh = blockIdx.x;
  int qblk = blockIdx.y;
  int b = bh >> 4, h = bh & 15;
  int tid = threadIdx.x, w = tid >> 6, lane = tid & 63, lr = lane & 15, lq = lane >> 4;

  __shared__ f16 Ksh[2][64 * 72];
  __shared__ f16 Vsh[2][64 * 72];

  // Q fragments: 4 q-tiles of 16, scale 1/8 * log2(e) folded (exp2 path)
  f16x8 qf[4][2];
#pragma unroll
  for (int qt = 0; qt < 4; qt++) {
    const f16* Qbase =
        Qh + ((size_t)bh * SEQL + qblk * 256 + w * 64 + qt * 16 + lr) * DH;
#pragma unroll
    for (int ks = 0; ks < 2; ks++) {
      qf[qt][ks] = *(const f16x8*)(Qbase + ks * 32 + lq * 8);
      qf[qt][ks] = qf[qt][ks] * (f16)0.18033688f;
    }
  }

  f32x4 O[4][4];
#pragma unroll
  for (int qt = 0; qt < 4; qt++)
#pragma unroll
    for (int dt = 0; dt < 4; dt++) O[qt][dt] = (f32x4){0.f, 0.f, 0.f, 0.f};
  float lsum[4] = {0.f, 0.f, 0.f, 0.f};

  int srow = tid >> 3, sseg = tid & 7, srow1 = srow + 32;
  const f16* Kg0 = Kh + ((size_t)bh * SEQL + srow) * DH + sseg * 8;
  const f16* Kg1 = Kh + ((size_t)bh * SEQL + srow1) * DH + sseg * 8;
  const f16* Vg0 = Vp + ((size_t)bh * DH + srow) * SEQL + sseg * 8;
  const f16* Vg1 = Vp + ((size_t)bh * DH + srow1) * SEQL + sseg * 8;

  uint4 kr0 = *(const uint4*)(Kg0), kr1 = *(const uint4*)(Kg1);
  uint4 vr0 = *(const uint4*)(Vg0), vr1 = *(const uint4*)(Vg1);

  for (int kb = 0; kb < SEQL / 64; kb++) {
    f16* Kp = Ksh[kb & 1];
    f16* Vq = Vsh[kb & 1];
    *(uint4*)(Kp + srow * 72 + sseg * 8) = kr0;
    *(uint4*)(Kp + srow1 * 72 + sseg * 8) = kr1;
    *(uint4*)(Vq + srow * 72 + sseg * 8) = vr0;
    *(uint4*)(Vq + srow1 * 72 + sseg * 8) = vr1;
    if (kb < SEQL / 64 - 1) {
      size_t ko = (size_t)(kb + 1) * 64 * DH;
      int vo = (kb + 1) * 64;
      kr0 = *(const uint4*)(Kg0 + ko);
      kr1 = *(const uint4*)(Kg1 + ko);
      vr0 = *(const uint4*)(Vg0 + vo);
      vr1 = *(const uint4*)(Vg1 + vo);
    }
    __syncthreads();

    // S^T[key][q]: K fragments shared across all 4 q-tiles
    f32x4 sacc[4][4];
#pragma unroll
    for (int qt = 0; qt < 4; qt++)
#pragma unroll
      for (int kt = 0; kt < 4; kt++) sacc[qt][kt] = (f32x4){0.f, 0.f, 0.f, 0.f};
#pragma unroll
    for (int ks = 0; ks < 2; ks++) {
#pragma unroll
      for (int kt = 0; kt < 4; kt++) {
        f16x8 kf = *(const f16x8*)(Kp + (kt * 16 + lr) * 72 + ks * 32 + lq * 8);
        sacc[0][kt] = mfma16(kf, qf[0][ks], sacc[0][kt]);
        sacc[1][kt] = mfma16(kf, qf[1][ks], sacc[1][kt]);
        sacc[2][kt] = mfma16(kf, qf[2][ks], sacc[2][kt]);
        sacc[3][kt] = mfma16(kf, qf[3][ks], sacc[3][kt]);
      }
    }

    // p = exp2(s); in-lane partial sums; pack into PV B-fragments
    f16x8 pf[4][2];
#pragma unroll
    for (int qt = 0; qt < 4; qt++) {
      float part = 0.f;
#pragma unroll
      for (int kt = 0; kt < 4; kt++) {
        float p0 = __builtin_amdgcn_exp2f(sacc[qt][kt][0]);
        float p1 = __builtin_amdgcn_exp2f(sacc[qt][kt][1]);
        float p2 = __builtin_amdgcn_exp2f(sacc[qt][kt][2]);
        float p3 = __builtin_amdgcn_exp2f(sacc[qt][kt][3]);
        part += (p0 + p1) + (p2 + p3);
        int s = kt >> 1, off = (kt & 1) * 4;
        pf[qt][s][off + 0] = (f16)p0; pf[qt][s][off + 1] = (f16)p1;
        pf[qt][s][off + 2] = (f16)p2; pf[qt][s][off + 3] = (f16)p3;
      }
      lsum[qt] += part;
    }

    // O^T[d][q] += V^T P^T ; V fragments shared across all 4 q-tiles
#pragma unroll
    for (int s = 0; s < 2; s++) {
#pragma unroll
      for (int dt = 0; dt < 4; dt++) {
        f16x8 vf = *(const f16x8*)(Vq + (dt * 16 + lr) * 72 + s * 32 + lq * 8);
        O[0][dt] = mfma16(vf, pf[0][s], O[0][dt]);
        O[1][dt] = mfma16(vf, pf[1][s], O[1][dt]);
        O[2][dt] = mfma16(vf, pf[2][s], O[2][dt]);
        O[3][dt] = mfma16(vf, pf[3][s], O[3][dt]);
      }
    }
  }

#pragma unroll
  for (int qt = 0; qt < 4; qt++) {
    float l1 = lsum[qt] + __shfl_xor(lsum[qt], 16);
    float ltot = l1 + __shfl_xor(l1, 32);
    float inv = 1.0f / ltot;
    int q = qblk * 256 + w * 64 + qt * 16 + lr;
    f16* dst = Ao + ((size_t)b * SEQL + q) * HID + h * DH;
#pragma unroll
    for (int dt = 0; dt < 4; dt++) {
      f16x4 o = { (f16)(O[qt][dt][0] * inv), (f16)(O[qt][dt][1] * inv),
                  (f16)(O[qt][dt][2] * inv), (f16)(O[qt][dt][3] * inv) };
      *(f16x4*)(dst + dt * 16 + lq * 4) = o;
    }
  }
}

// ---------------------------------------------------------------- out GEMM
__global__ __launch_bounds__(256, 2) void k_gemm_out(const f16* __restrict__ Ah,
                                                     const f16* __restrict__ WoT,
                                                     const float* __restrict__ bo,
                                                     float* __restrict__ out) {
  constexpr int K = HID;
  int m0 = blockIdx.x * 128, n0 = blockIdx.y * 64;
  int tid = threadIdx.x;
  int w = tid >> 6, lane = tid & 63, lr = lane & 15, lq = lane >> 4;
  int wm = w >> 1, wn = w & 1;
  __shared__ f16 Ash[128 * 32];
  __shared__ f16 Bsh[64 * 32];
  f32x4 acc[4][2];
#pragma unroll
  for (int i = 0; i < 4; i++)
#pragma unroll
    for (int j = 0; j < 2; j++) acc[i][j] = (f32x4){0.f, 0.f, 0.f, 0.f};

  int row0 = tid >> 2, seg0 = tid & 3;
  int row1 = (256 + tid) >> 2;
  const f16* Ag0 = Ah + (size_t)(m0 + row0) * K + seg0 * 8;
  const f16* Ag1 = Ah + (size_t)(m0 + row1) * K + seg0 * 8;
  const f16* Bg0 = WoT + (size_t)(n0 + row0) * K + seg0 * 8;

  for (int k0 = 0; k0 < K; k0 += 32) {
    __syncthreads();
    gld16(Ag0 + k0, Ash + tid * 8);
    gld16(Ag1 + k0, Ash + (256 + tid) * 8);
    gld16(Bg0 + k0, Bsh + tid * 8);
    __syncthreads();
    f16x8 af[4], bfr[2];
#pragma unroll
    for (int mt = 0; mt < 4; mt++)
      af[mt] = *(const f16x8*)(Ash + (wm * 64 + mt * 16 + lr) * 32 + lq * 8);
#pragma unroll
    for (int nt = 0; nt < 2; nt++)
      bfr[nt] = *(const f16x8*)(Bsh + (wn * 32 + nt * 16 + lr) * 32 + lq * 8);
#pragma unroll
    for (int mt = 0; mt < 4; mt++)
#pragma unroll
      for (int nt = 0; nt < 2; nt++)
        acc[mt][nt] = mfma16(af[mt], bfr[nt], acc[mt][nt]);
  }

#pragma unroll
  for (int nt = 0; nt < 2; nt++) {
    int o = n0 + wn * 32 + nt * 16 + lr;
    float bias = bo[o];
#pragma unroll
    for (int mt = 0; mt < 4; mt++) {
      int t0 = m0 + wm * 64 + mt * 16 + lq * 4;
#pragma unroll
      for (int r = 0; r < 4; r++)
        out[(size_t)(t0 + r) * HID + o] = acc[mt][nt][r] + bias;
    }
  }
}

// ---------------------------------------------------------------- launch
extern "C" void kernel_launch(void* const* d_in, const int* in_sizes, int n_in,
                              void* d_out, int out_size, void* d_ws, size_t ws_size,
                              hipStream_t stream) {
  const float* x  = (const float*)d_in[0];
  const float* Wq = (const float*)d_in[1];
  const float* bq = (const float*)d_in[2];
  const float* Wk = (const float*)d_in[3];
  const float* bk = (const float*)d_in[4];
  const float* Wv = (const float*)d_in[5];
  const float* bv = (const float*)d_in[6];
  const float* Wo = (const float*)d_in[7];
  const float* bo = (const float*)d_in[8];

  char* ws = (char*)d_ws;
  f16* xh  = (f16*)(ws + 0);                       //  8 MiB
  f16* WT  = (f16*)(ws + 8388608);                 //  6 MiB
  f16* WoT = (f16*)(ws + 14680064);                //  2 MiB
  f16* Qh  = (f16*)(ws + 16777216);                //  8 MiB [bh][s][d]
  f16* Kh  = (f16*)(ws + 25165824);                //  8 MiB [bh][s][d]
  f16* Vp  = (f16*)(ws + 33554432);                //  8 MiB [bh][d][key']
  f16* Ao  = (f16*)(ws + 41943040);                //  8 MiB [b][s][h*dv]

  k_convert_x<<<TOK * HID / 1024, 256, 0, stream>>>(x, xh);
  k_transpose<<<dim3(32, 32, 4), 256, 0, stream>>>(Wq, Wk, Wv, Wo, WT, WoT);
  k_gemm_qkv<<<dim3(TOK / 128, NQKV / 128), 256, 0, stream>>>(xh, WT, bq, bk, bv,
                                                              Qh, Kh, Vp);
  k_attn<<<dim3(BATCH * NH, SEQL / 256), 256, 0, stream>>>(Qh, Kh, Vp, Ao);
  k_gemm_out<<<dim3(TOK / 128, HID / 64), 256, 0, stream>>>(Ao, WoT, bo,
                                                            (float*)d_out);
}

// Round 2
// 179.827 us; speedup vs baseline: 1.0739x; 1.0739x over previous
//
#include <hip/hip_runtime.h>
#include <cstdint>
#include <cstddef>

using f16   = _Float16;
using f16x4 = __attribute__((ext_vector_type(4))) _Float16;
using f16x8 = __attribute__((ext_vector_type(8))) _Float16;
using f32x4 = __attribute__((ext_vector_type(4))) float;

__device__ __forceinline__ f32x4 mfma16(f16x8 a, f16x8 b, f32x4 c) {
  return __builtin_amdgcn_mfma_f32_16x16x32_f16(a, b, c, 0, 0, 0);
}

__device__ __forceinline__ void gld16(const f16* g, f16* l) {
  __builtin_amdgcn_global_load_lds(
      (__attribute__((address_space(1))) void*)g,
      (__attribute__((address_space(3))) void*)l, 16, 0, 0);
}

constexpr int BATCH = 2, SEQL = 2048, HID = 1024, NH = 16, DH = 64;
constexpr int TOK = BATCH * SEQL;   // 4096
constexpr int NQKV = 3 * HID;       // 3072

// ---------------------------------------------------------------- prep
__global__ __launch_bounds__(256) void k_convert_x(const float* __restrict__ x,
                                                   f16* __restrict__ xh) {
  int i = (blockIdx.x * 256 + threadIdx.x) * 4;
  float4 v = *(const float4*)(x + i);
  f16x4 o = { (f16)v.x, (f16)v.y, (f16)v.z, (f16)v.w };
  *(f16x4*)(xh + i) = o;
}

__global__ __launch_bounds__(256) void k_transpose(const float* __restrict__ Wq,
                                                   const float* __restrict__ Wk,
                                                   const float* __restrict__ Wv,
                                                   const float* __restrict__ Wo,
                                                   f16* __restrict__ WT,
                                                   f16* __restrict__ WoT) {
  __shared__ float tile[32][33];
  int mat = blockIdx.z;
  const float* W = (mat == 0) ? Wq : (mat == 1) ? Wk : (mat == 2) ? Wv : Wo;
  int in0 = blockIdx.x * 32, out0 = blockIdx.y * 32;
  int c = threadIdx.x & 31, r8 = threadIdx.x >> 5;
#pragma unroll
  for (int i = 0; i < 4; i++) {
    int r = r8 + i * 8;
    tile[r][c] = W[(size_t)(in0 + r) * HID + out0 + c];
  }
  __syncthreads();
#pragma unroll
  for (int i = 0; i < 4; i++) {
    int r = r8 + i * 8;
    f16 v = (f16)tile[c][r];
    if (mat == 3) WoT[(size_t)(out0 + r) * HID + in0 + c] = v;
    else          WT[(size_t)(mat * HID + out0 + r) * HID + in0 + c] = v;
  }
}

// ---------------------------------------------------------------- QKV GEMM
// 128x128 block tile, BK=32, async staging. V is stored TRANSPOSED [d][key']
// with keys pre-permuted (key'=(k&~31)|((k&12)<<1)|((k>>2)&4)|(k&3)) so the
// attention kernel's V A-fragments are contiguous 16B LDS reads.
__global__ __launch_bounds__(256, 2) void k_gemm_qkv(
    const f16* __restrict__ xh, const f16* __restrict__ WT,
    const float* __restrict__ bq, const float* __restrict__ bk,
    const float* __restrict__ bv,
    f16* __restrict__ Qh, f16* __restrict__ Kh, f16* __restrict__ Vp) {
  constexpr int K = HID;
  int m0 = blockIdx.x * 128, n0 = blockIdx.y * 128;
  int tid = threadIdx.x;
  int w = tid >> 6, lane = tid & 63, lr = lane & 15, lq = lane >> 4;
  int wm = w >> 1, wn = w & 1;
  __shared__ f16 Ash[128 * 32];
  __shared__ f16 Bsh[128 * 32];
  f32x4 acc[4][4];
#pragma unroll
  for (int i = 0; i < 4; i++)
#pragma unroll
    for (int j = 0; j < 4; j++) acc[i][j] = (f32x4){0.f, 0.f, 0.f, 0.f};

  int row0 = tid >> 2, seg0 = tid & 3;
  int row1 = (256 + tid) >> 2;
  const f16* Ag0 = xh + (size_t)(m0 + row0) * K + seg0 * 8;
  const f16* Ag1 = xh + (size_t)(m0 + row1) * K + seg0 * 8;
  const f16* Bg0 = WT + (size_t)(n0 + row0) * K + seg0 * 8;
  const f16* Bg1 = WT + (size_t)(n0 + row1) * K + seg0 * 8;

  for (int k0 = 0; k0 < K; k0 += 32) {
    __syncthreads();
    gld16(Ag0 + k0, Ash + tid * 8);
    gld16(Ag1 + k0, Ash + (256 + tid) * 8);
    gld16(Bg0 + k0, Bsh + tid * 8);
    gld16(Bg1 + k0, Bsh + (256 + tid) * 8);
    __syncthreads();
    f16x8 af[4], bfr[4];
#pragma unroll
    for (int mt = 0; mt < 4; mt++)
      af[mt] = *(const f16x8*)(Ash + (wm * 64 + mt * 16 + lr) * 32 + lq * 8);
#pragma unroll
    for (int nt = 0; nt < 4; nt++)
      bfr[nt] = *(const f16x8*)(Bsh + (wn * 64 + nt * 16 + lr) * 32 + lq * 8);
#pragma unroll
    for (int mt = 0; mt < 4; mt++)
#pragma unroll
      for (int nt = 0; nt < 4; nt++)
        acc[mt][nt] = mfma16(af[mt], bfr[nt], acc[mt][nt]);
  }

#pragma unroll
  for (int nt = 0; nt < 4; nt++) {
    int o = n0 + wn * 64 + nt * 16 + lr;
    int sec = o >> 10, o1 = o & 1023, hh = o1 >> 6, dd = o1 & 63;
    float bias = (sec == 0) ? bq[o1] : (sec == 1) ? bk[o1] : bv[o1];
#pragma unroll
    for (int mt = 0; mt < 4; mt++) {
      int t0 = m0 + wm * 64 + mt * 16 + lq * 4;
      int b = t0 >> 11, s0 = t0 & (SEQL - 1);
      size_t bh = (size_t)(b * NH + hh);
      if (sec == 2) {
        f16x4 pv = { (f16)(acc[mt][nt][0] + bias), (f16)(acc[mt][nt][1] + bias),
                     (f16)(acc[mt][nt][2] + bias), (f16)(acc[mt][nt][3] + bias) };
        int pb = (s0 & ~31) | ((s0 & 12) << 1) | ((s0 >> 2) & 4);
        *(f16x4*)(Vp + (bh * DH + dd) * SEQL + pb) = pv;   // V^T, permuted keys
      } else {
        f16* dst = (sec == 0) ? Qh : Kh;
#pragma unroll
        for (int r = 0; r < 4; r++)
          dst[(bh * SEQL + s0 + r) * DH + dd] = (f16)(acc[mt][nt][r] + bias);
      }
    }
  }
}

// ---------------------------------------------------------------- attention
// grid (x=bh 32, y=qblk 8): bh fastest => all blocks of one bh land on the
// same XCD (id%8 = bh%8) -> K/V stay L2-resident.
// 512 threads = 8 waves. KEY-SPLIT: waves 0-3 process keys 0-1023, waves 4-7
// keys 1024-2047, each group with private double-buffered K/V LDS. Each wave
// owns 64 q (4 q-tiles of 16) -> each K/V LDS fragment feeds 4 MFMAs (low
// LDS-pipe demand) while the block still carries 8 waves = 2/SIMD (latency
// hiding). Softmax is max-free (pure exp2) so the two key-halves' partial
// (O, lsum) merge by addition via a slot-XOR-swizzled LDS exchange.
// S computed transposed (A=K, B=Q); softmax over keys is in-lane, P's
// B-fragment is the packed exp results (no LDS trip).
__global__ __launch_bounds__(512, 2) void k_attn(const f16* __restrict__ Qh,
                                                 const f16* __restrict__ Kh,
                                                 const f16* __restrict__ Vp,
                                                 f16* __restrict__ Ao) {
  int bh = blockIdx.x;
  int qblk = blockIdx.y;
  int b = bh >> 4, h = bh & 15;
  int tid = threadIdx.x;
  int w = tid >> 6;          // 0..7
  int g = w >> 2;            // key-half group
  int wq = w & 3;            // q position within block
  int lane = tid & 63, lr = lane & 15, lq = lane >> 4;

  // [group][buf][K|V] tiles of 64x72 f16 = 73728 B total
  __shared__ f16 sh[8 * 64 * 72];

  // Q fragments: 4 q-tiles of 16, scale 1/8 * log2(e) folded (exp2 path)
  f16x8 qf[4][2];
#pragma unroll
  for (int qt = 0; qt < 4; qt++) {
    const f16* Qbase =
        Qh + ((size_t)bh * SEQL + qblk * 256 + wq * 64 + qt * 16 + lr) * DH;
#pragma unroll
    for (int ks = 0; ks < 2; ks++) {
      qf[qt][ks] = *(const f16x8*)(Qbase + ks * 32 + lq * 8);
      qf[qt][ks] = qf[qt][ks] * (f16)0.18033688f;
    }
  }

  f32x4 O[4][4];
#pragma unroll
  for (int qt = 0; qt < 4; qt++)
#pragma unroll
    for (int dt = 0; dt < 4; dt++) O[qt][dt] = (f32x4){0.f, 0.f, 0.f, 0.f};
  float lsum[4] = {0.f, 0.f, 0.f, 0.f};

  // staging: 256 threads per group stage that group's 64-key tile
  int gtid = tid & 255;
  int srow = gtid >> 3, sseg = gtid & 7, srow1 = srow + 32;
  int kbase = g * 1024;
  const f16* Kg0 = Kh + ((size_t)bh * SEQL + kbase + srow) * DH + sseg * 8;
  const f16* Kg1 = Kh + ((size_t)bh * SEQL + kbase + srow1) * DH + sseg * 8;
  const f16* Vg0 = Vp + ((size_t)bh * DH + srow) * SEQL + kbase + sseg * 8;
  const f16* Vg1 = Vp + ((size_t)bh * DH + srow1) * SEQL + kbase + sseg * 8;

  uint4 kr0 = *(const uint4*)(Kg0), kr1 = *(const uint4*)(Kg1);
  uint4 vr0 = *(const uint4*)(Vg0), vr1 = *(const uint4*)(Vg1);

  for (int kb = 0; kb < 16; kb++) {
    f16* Kp = sh + ((g * 2 + (kb & 1)) * 2 + 0) * 4608;
    f16* Vq = Kp + 4608;
    *(uint4*)(Kp + srow * 72 + sseg * 8) = kr0;
    *(uint4*)(Kp + srow1 * 72 + sseg * 8) = kr1;
    *(uint4*)(Vq + srow * 72 + sseg * 8) = vr0;
    *(uint4*)(Vq + srow1 * 72 + sseg * 8) = vr1;
    if (kb < 15) {
      size_t ko = (size_t)(kb + 1) * 64 * DH;
      int vo = (kb + 1) * 64;
      kr0 = *(const uint4*)(Kg0 + ko);
      kr1 = *(const uint4*)(Kg1 + ko);
      vr0 = *(const uint4*)(Vg0 + vo);
      vr1 = *(const uint4*)(Vg1 + vo);
    }
    __syncthreads();

    // S^T[key][q]: K fragments shared across all 4 q-tiles
    f32x4 sacc[4][4];
#pragma unroll
    for (int qt = 0; qt < 4; qt++)
#pragma unroll
      for (int kt = 0; kt < 4; kt++) sacc[qt][kt] = (f32x4){0.f, 0.f, 0.f, 0.f};
#pragma unroll
    for (int ks = 0; ks < 2; ks++) {
#pragma unroll
      for (int kt = 0; kt < 4; kt++) {
        f16x8 kf = *(const f16x8*)(Kp + (kt * 16 + lr) * 72 + ks * 32 + lq * 8);
        sacc[0][kt] = mfma16(kf, qf[0][ks], sacc[0][kt]);
        sacc[1][kt] = mfma16(kf, qf[1][ks], sacc[1][kt]);
        sacc[2][kt] = mfma16(kf, qf[2][ks], sacc[2][kt]);
        sacc[3][kt] = mfma16(kf, qf[3][ks], sacc[3][kt]);
      }
    }

    // p = exp2(s); in-lane partial sums; pack into PV B-fragments
    f16x8 pf[4][2];
#pragma unroll
    for (int qt = 0; qt < 4; qt++) {
      float part = 0.f;
#pragma unroll
      for (int kt = 0; kt < 4; kt++) {
        float p0 = __builtin_amdgcn_exp2f(sacc[qt][kt][0]);
        float p1 = __builtin_amdgcn_exp2f(sacc[qt][kt][1]);
        float p2 = __builtin_amdgcn_exp2f(sacc[qt][kt][2]);
        float p3 = __builtin_amdgcn_exp2f(sacc[qt][kt][3]);
        part += (p0 + p1) + (p2 + p3);
        int s = kt >> 1, off = (kt & 1) * 4;
        pf[qt][s][off + 0] = (f16)p0; pf[qt][s][off + 1] = (f16)p1;
        pf[qt][s][off + 2] = (f16)p2; pf[qt][s][off + 3] = (f16)p3;
      }
      lsum[qt] += part;
    }

    // O^T[d][q] += V^T P^T ; V fragments shared across all 4 q-tiles
#pragma unroll
    for (int s = 0; s < 2; s++) {
#pragma unroll
      for (int dt = 0; dt < 4; dt++) {
        f16x8 vf = *(const f16x8*)(Vq + (dt * 16 + lr) * 72 + s * 32 + lq * 8);
        O[0][dt] = mfma16(vf, pf[0][s], O[0][dt]);
        O[1][dt] = mfma16(vf, pf[1][s], O[1][dt]);
        O[2][dt] = mfma16(vf, pf[2][s], O[2][dt]);
        O[3][dt] = mfma16(vf, pf[3][s], O[3][dt]);
      }
    }
  }

  // ---- merge the two key-halves via LDS (slot-XOR swizzle: conflict-free)
  __syncthreads();
  float* part = (float*)sh;          // [256 q][16 slots of 16B]
  float* plsum = part + 16384;       // [256 q][4 lq]
  if (g == 1) {
#pragma unroll
    for (int qt = 0; qt < 4; qt++) {
      int ql = wq * 64 + qt * 16 + lr;
#pragma unroll
      for (int dt = 0; dt < 4; dt++) {
        int slot = (dt * 4 + lq) ^ lr;
        *(f32x4*)(part + ql * 64 + slot * 4) = O[qt][dt];
      }
      plsum[ql * 4 + lq] = lsum[qt];
    }
  }
  __syncthreads();
  if (g == 0) {
#pragma unroll
    for (int qt = 0; qt < 4; qt++) {
      int ql = wq * 64 + qt * 16 + lr;
      float ls = lsum[qt] + plsum[ql * 4 + lq];
      float l1 = ls + __shfl_xor(ls, 16);
      float ltot = l1 + __shfl_xor(l1, 32);
      float inv = 1.0f / ltot;
      int q = qblk * 256 + ql;
      f16* dst = Ao + ((size_t)b * SEQL + q) * HID + h * DH;
#pragma unroll
      for (int dt = 0; dt < 4; dt++) {
        int slot = (dt * 4 + lq) ^ lr;
        f32x4 po = *(const f32x4*)(part + ql * 64 + slot * 4);
        f16x4 o = { (f16)((O[qt][dt][0] + po[0]) * inv),
                    (f16)((O[qt][dt][1] + po[1]) * inv),
                    (f16)((O[qt][dt][2] + po[2]) * inv),
                    (f16)((O[qt][dt][3] + po[3]) * inv) };
        *(f16x4*)(dst + dt * 16 + lq * 4) = o;
      }
    }
  }
}

// ---------------------------------------------------------------- out GEMM
__global__ __launch_bounds__(256, 2) void k_gemm_out(const f16* __restrict__ Ah,
                                                     const f16* __restrict__ WoT,
                                                     const float* __restrict__ bo,
                                                     float* __restrict__ out) {
  constexpr int K = HID;
  int m0 = blockIdx.x * 128, n0 = blockIdx.y * 64;
  int tid = threadIdx.x;
  int w = tid >> 6, lane = tid & 63, lr = lane & 15, lq = lane >> 4;
  int wm = w >> 1, wn = w & 1;
  __shared__ f16 Ash[128 * 32];
  __shared__ f16 Bsh[64 * 32];
  f32x4 acc[4][2];
#pragma unroll
  for (int i = 0; i < 4; i++)
#pragma unroll
    for (int j = 0; j < 2; j++) acc[i][j] = (f32x4){0.f, 0.f, 0.f, 0.f};

  int row0 = tid >> 2, seg0 = tid & 3;
  int row1 = (256 + tid) >> 2;
  const f16* Ag0 = Ah + (size_t)(m0 + row0) * K + seg0 * 8;
  const f16* Ag1 = Ah + (size_t)(m0 + row1) * K + seg0 * 8;
  const f16* Bg0 = WoT + (size_t)(n0 + row0) * K + seg0 * 8;

  for (int k0 = 0; k0 < K; k0 += 32) {
    __syncthreads();
    gld16(Ag0 + k0, Ash + tid * 8);
    gld16(Ag1 + k0, Ash + (256 + tid) * 8);
    gld16(Bg0 + k0, Bsh + tid * 8);
    __syncthreads();
    f16x8 af[4], bfr[2];
#pragma unroll
    for (int mt = 0; mt < 4; mt++)
      af[mt] = *(const f16x8*)(Ash + (wm * 64 + mt * 16 + lr) * 32 + lq * 8);
#pragma unroll
    for (int nt = 0; nt < 2; nt++)
      bfr[nt] = *(const f16x8*)(Bsh + (wn * 32 + nt * 16 + lr) * 32 + lq * 8);
#pragma unroll
    for (int mt = 0; mt < 4; mt++)
#pragma unroll
      for (int nt = 0; nt < 2; nt++)
        acc[mt][nt] = mfma16(af[mt], bfr[nt], acc[mt][nt]);
  }

#pragma unroll
  for (int nt = 0; nt < 2; nt++) {
    int o = n0 + wn * 32 + nt * 16 + lr;
    float bias = bo[o];
#pragma unroll
    for (int mt = 0; mt < 4; mt++) {
      int t0 = m0 + wm * 64 + mt * 16 + lq * 4;
#pragma unroll
      for (int r = 0; r < 4; r++)
        out[(size_t)(t0 + r) * HID + o] = acc[mt][nt][r] + bias;
    }
  }
}

// ---------------------------------------------------------------- launch
extern "C" void kernel_launch(void* const* d_in, const int* in_sizes, int n_in,
                              void* d_out, int out_size, void* d_ws, size_t ws_size,
                              hipStream_t stream) {
  const float* x  = (const float*)d_in[0];
  const float* Wq = (const float*)d_in[1];
  const float* bq = (const float*)d_in[2];
  const float* Wk = (const float*)d_in[3];
  const float* bk = (const float*)d_in[4];
  const float* Wv = (const float*)d_in[5];
  const float* bv = (const float*)d_in[6];
  const float* Wo = (const float*)d_in[7];
  const float* bo = (const float*)d_in[8];

  char* ws = (char*)d_ws;
  f16* xh  = (f16*)(ws + 0);                       //  8 MiB
  f16* WT  = (f16*)(ws + 8388608);                 //  6 MiB
  f16* WoT = (f16*)(ws + 14680064);                //  2 MiB
  f16* Qh  = (f16*)(ws + 16777216);                //  8 MiB [bh][s][d]
  f16* Kh  = (f16*)(ws + 25165824);                //  8 MiB [bh][s][d]
  f16* Vp  = (f16*)(ws + 33554432);                //  8 MiB [bh][d][key']
  f16* Ao  = (f16*)(ws + 41943040);                //  8 MiB [b][s][h*dv]

  k_convert_x<<<TOK * HID / 1024, 256, 0, stream>>>(x, xh);
  k_transpose<<<dim3(32, 32, 4), 256, 0, stream>>>(Wq, Wk, Wv, Wo, WT, WoT);
  k_gemm_qkv<<<dim3(TOK / 128, NQKV / 128), 256, 0, stream>>>(xh, WT, bq, bk, bv,
                                                              Qh, Kh, Vp);
  k_attn<<<dim3(BATCH * NH, SEQL / 256), 512, 0, stream>>>(Qh, Kh, Vp, Ao);
  k_gemm_out<<<dim3(TOK / 128, HID / 64), 256, 0, stream>>>(Ao, WoT, bo,
                                                            (float*)d_out);
}